// Round 15
// baseline (161.950 us; speedup 1.0000x reference)
//
#include <hip/hip_runtime.h>
#include <math.h>

#define D 64
#define KNOTS 32
#define NSEG 31
#define G 384    // lookup cells per dim; tab row stride == G (bug fixed r15)
#define SPAD 32  // sA/sB row stride (f32)

typedef float f4v __attribute__((ext_vector_type(4)));

__device__ __forceinline__ float softplus_f(float v) {
  return fmaxf(v, 0.f) + log1pf(expf(-fabsf(v)));
}

// Fused PWL spline. u8 table = segment of each cell CENTER (error <= |dA|*w
// per in-cell knot, ~0.03-0.13 << 0.186 at G=384; boundary cells pinned ->
// exact tail extrapolation). r15 = r14 with the tab indexing fixed:
// tab[sd*G + c] (r14 used a 64-wide stride against 384-long rows -> aliasing).
// Asm pipeline unchanged from r12 (verified): wait -> compute -> load-next ->
// store; peel vmcnt 8/12/16, steady 20; queue [L,S,L,S...] keeps awaited
// loads oldest; r_ live across GLOADI forbids store-data aliasing.
// LDS 48KB -> 3 blocks/CU = 24 waves/CU at (512,4) 128-VGPR budget.
__global__ __launch_bounds__(512, 4) void pwl_fused(
    const float* __restrict__ x, const float* __restrict__ xk,
    const float* __restrict__ delta_raw, const float* __restrict__ scale_raw,
    const float* __restrict__ shift, float* __restrict__ out, int nrows) {
  __shared__ float kL[KNOTS * D];          // [j][sd]  8192 B
  __shared__ float sA[D * SPAD];           // [sd][s]  8192 B
  __shared__ float sB[D * SPAD];           // [sd][s]  8192 B
  __shared__ unsigned char tab[D * G];     // [sd][c] 24576 B  (total 49152)

  const int tid = threadIdx.x;

  // ---- stage knots transposed + swizzled: d=4q+r -> sd=q+16r ----
  for (int i = tid; i < D * KNOTS; i += blockDim.x) {
    int d = i >> 5, j = i & 31;
    int sd = (d >> 2) | ((d & 3) << 4);
    kL[j * D + sd] = xk[i];
  }
  __syncthreads();

  // ---- one thread per (swizzled) dim: exact A/B; inv -> kL row 0 ----
  if (tid < D) {
    const int sd = tid;
    const int d = ((sd & 15) << 2) | (sd >> 4);
    float num = 0.f, den = 0.f;
    for (int s = 0; s < NSEG; ++s) {
      float sp = softplus_f(delta_raw[d * NSEG + s]) + 1e-4f;
      float dx = kL[(s + 1) * D + sd] - kL[s * D + sd];
      num += sp * dx;
      den += dx;
    }
    float avg = fmaxf(num / (den + 1e-8f), 1e-6f);
    float scale = softplus_f(scale_raw[d]) + 1e-3f;
    float sh = shift[d];
    float y = 0.f;
    for (int s = 0; s < NSEG; ++s) {
      float sp = softplus_f(delta_raw[d * NSEG + s]) + 1e-4f;
      float m = sp / avg;
      float k0 = kL[s * D + sd];
      sA[sd * SPAD + s] = m * scale;
      sB[sd * SPAD + s] = (y - m * k0) * scale + sh;
      y += m * (kL[(s + 1) * D + sd] - k0);
    }
    float lo = kL[1 * D + sd];
    float hi = kL[(KNOTS - 1) * D + sd];
    kL[0 * D + sd] = (float)G / (hi - lo);  // row 0 (knot0) dead -> inv
  }
  __syncthreads();

  // ---- build tab: segment at each cell CENTER (binary search rows 1..31) ----
  for (int p = tid; p < G * D; p += blockDim.x) {
    const int sd = p & 63;
    const int c = p >> 6;
    const float lo = kL[1 * D + sd];
    const float hi = kL[(KNOTS - 1) * D + sd];
    const float w = (hi - lo) / (float)G;
    const float xc = fmaf((float)c + 0.5f, w, lo);
    int b = 0;
#pragma unroll
    for (int half = 16; half > 0; half >>= 1) {
      b += (kL[(b + half) * D + sd] < xc) ? half : 0;  // count knots[1..31] < xc
    }
    int i0 = min(b, 30);
    if (c == 0) i0 = 0;        // exact left-tail extrapolation
    if (c == G - 1) i0 = 30;   // exact right-tail extrapolation
    tab[sd * G + c] = (unsigned char)i0;
  }
  __syncthreads();

  // ---- nlo -> kL row 1 (dead after tab build) ----
  if (tid < D) {
    float inv = kL[0 * D + tid];
    float nlo = -kL[1 * D + tid] * inv;
    kL[1 * D + tid] = nlo;
  }
  __syncthreads();

  // ---- main loop: lane owns dims 4q..4q+3; asm pipeline (r12-verified) ----
  const int lane = tid & 63;
  const int q = lane & 15;
  const int sd0 = q, sd1 = q + 16, sd2 = q + 32, sd3 = q + 48;
  const float inv0 = kL[sd0], nlo0 = kL[D + sd0];
  const float inv1 = kL[sd1], nlo1 = kL[D + sd1];
  const float inv2 = kL[sd2], nlo2 = kL[D + sd2];
  const float inv3 = kL[sd3], nlo3 = kL[D + sd3];

  const float* xp = x;   // SGPR base for asm loads
  float* op = out;       // SGPR base for asm stores
  const f4v* __restrict__ x4 = (const f4v*)x;
  f4v* __restrict__ o4 = (f4v*)out;

  auto evalquad = [&](f4v xv) -> f4v {
    float cf0 = fminf(fmaxf(fmaf(xv.x, inv0, nlo0), 0.f), (float)(G - 1));
    float cf1 = fminf(fmaxf(fmaf(xv.y, inv1, nlo1), 0.f), (float)(G - 1));
    float cf2 = fminf(fmaxf(fmaf(xv.z, inv2, nlo2), 0.f), (float)(G - 1));
    float cf3 = fminf(fmaxf(fmaf(xv.w, inv3, nlo3), 0.f), (float)(G - 1));
    int i0 = tab[sd0 * G + (int)cf0];
    int i1 = tab[sd1 * G + (int)cf1];
    int i2 = tab[sd2 * G + (int)cf2];
    int i3 = tab[sd3 * G + (int)cf3];
    f4v r;
    r.x = fmaf(sA[sd0 * SPAD + i0], xv.x, sB[sd0 * SPAD + i0]);
    r.y = fmaf(sA[sd1 * SPAD + i1], xv.y, sB[sd1 * SPAD + i1]);
    r.z = fmaf(sA[sd2 * SPAD + i2], xv.z, sB[sd2 * SPAD + i2]);
    r.w = fmaf(sA[sd3 * SPAD + i3], xv.w, sB[sd3 * SPAD + i3]);
    return r;
  };

  const int wid = (int)(blockIdx.x * blockDim.x + tid) >> 6;
  const int nw = (int)(gridDim.x * blockDim.x) >> 6;
  const int ngroups = nrows >> 4;  // 16 rows/group = 256 f4v = 4096 B
  const int chunk = (ngroups + nw - 1) / nw;
  int g0 = wid * chunk;
  const int gend = min(g0 + chunk, ngroups);
  const int navail = (gend > g0) ? (gend - g0) : 0;
  const int nfull = (navail / 3) * 3;

  f4v A0, A1, A2, A3, B0, B1, B2, B3, C0, C1, C2, C3;

#define GLOADI(bk, voff)                                                 \
  asm volatile("global_load_dwordx4 %0, %4, %5 offset:0\n\t"             \
               "global_load_dwordx4 %1, %4, %5 offset:1024\n\t"          \
               "global_load_dwordx4 %2, %4, %5 offset:2048\n\t"          \
               "global_load_dwordx4 %3, %4, %5 offset:3072"              \
               : "=&v"(bk##0), "=&v"(bk##1), "=&v"(bk##2), "=&v"(bk##3)  \
               : "v"(voff), "s"(xp))

#define WAITP(NSTR)                                                 \
  asm volatile("s_waitcnt vmcnt(" NSTR ") expcnt(0)" ::: "memory"); \
  __builtin_amdgcn_sched_barrier(0)

  // wait -> compute -> load-next -> store
#define STEP(bk, NSTR)                                                   \
  {                                                                      \
    WAITP(NSTR);                                                         \
    f4v r0_ = evalquad(bk##0);                                           \
    f4v r1_ = evalquad(bk##1);                                           \
    f4v r2_ = evalquad(bk##2);                                           \
    f4v r3_ = evalquad(bk##3);                                           \
    GLOADI(bk, voffN);                                                   \
    voffN = min(voffN + 4096u, maxL);                                    \
    asm volatile("global_store_dwordx4 %4, %0, %5 offset:0 nt\n\t"       \
                 "global_store_dwordx4 %4, %1, %5 offset:1024 nt\n\t"    \
                 "global_store_dwordx4 %4, %2, %5 offset:2048 nt\n\t"    \
                 "global_store_dwordx4 %4, %3, %5 offset:3072 nt"        \
                 :: "v"(r0_), "v"(r1_), "v"(r2_), "v"(r3_),              \
                    "v"(voffS), "s"(op));                                \
    voffS += 4096u;                                                      \
  }

  if (nfull >= 3) {
    const unsigned lb = (unsigned)lane * 16u;
    const unsigned maxL = (unsigned)(ngroups - 1) * 4096u + lb;
    unsigned voffS = (unsigned)g0 * 4096u + lb;
    unsigned voffN = voffS;
    GLOADI(A, voffN); voffN += 4096u;   // g0
    GLOADI(B, voffN); voffN += 4096u;   // g0+1
    GLOADI(C, voffN);                   // g0+2
    voffN = min(voffN + 4096u, maxL);

    // peel: waits 8 / 12 / 16, then steady 20
    STEP(A, "8");
    STEP(B, "12");
    STEP(C, "16");
    const int trips3 = nfull / 3 - 1;
    for (int t = 0; t < trips3; ++t) {
      STEP(A, "20");
      STEP(B, "20");
      STEP(C, "20");
    }
    asm volatile("s_waitcnt vmcnt(0)" ::: "memory");
    __builtin_amdgcn_sched_barrier(0);
    g0 += nfull;
  }
#undef GLOADI
#undef WAITP
#undef STEP

  // ---- remainder groups (<=2 per wave): normal compiler path ----
  for (int g = g0; g < gend; ++g) {
    const int base = g * 256 + lane;
    f4v v0 = x4[base];
    f4v v1 = x4[base + 64];
    f4v v2 = x4[base + 128];
    f4v v3 = x4[base + 192];
    f4v r0 = evalquad(v0);
    f4v r1 = evalquad(v1);
    f4v r2 = evalquad(v2);
    f4v r3 = evalquad(v3);
    __builtin_nontemporal_store(r0, &o4[base]);
    __builtin_nontemporal_store(r1, &o4[base + 64]);
    __builtin_nontemporal_store(r2, &o4[base + 128]);
    __builtin_nontemporal_store(r3, &o4[base + 192]);
  }

  // ---- tail rows (nrows % 16): quarter-wave per row (unused at 1e6) ----
  const int tr0 = ngroups << 4;
  for (int r = tr0 + wid; r < nrows; r += nw) {
    if (lane < 16) {
      const int bi = r * 16 + q;
      f4v xv = x4[bi];
      f4v rv = evalquad(xv);
      __builtin_nontemporal_store(rv, &o4[bi]);
    }
  }
}

extern "C" void kernel_launch(void* const* d_in, const int* in_sizes, int n_in,
                              void* d_out, int out_size, void* d_ws, size_t ws_size,
                              hipStream_t stream) {
  const float* x = (const float*)d_in[0];          // [N, D]
  const float* xk = (const float*)d_in[1];         // [D, K]
  const float* delta_raw = (const float*)d_in[2];  // [D, K-1]
  const float* scale_raw = (const float*)d_in[3];  // [D]
  const float* shift = (const float*)d_in[4];      // [D]
  float* out = (float*)d_out;

  const int nrows = in_sizes[0] / D;  // 1,000,000
  const int block = 512;              // 8 waves; LDS 48 KB -> 3 blocks/CU
  const int grid = 768;               // 3 per CU -> 24 waves/CU
  pwl_fused<<<grid, block, 0, stream>>>(x, xk, delta_raw, scale_raw, shift,
                                        out, nrows);
}